// Round 11
// baseline (445.990 us; speedup 1.0000x reference)
//
#include <hip/hip_runtime.h>
#include <math.h>

#define B_ 4
#define C_ 64
#define M_ 8
#define H_ 224
#define W_ 224
#define N_ (H_*W_)        // 50176
#define CN_ (C_*N_)       // 3211264
#define MN_ (M_*N_)       // 401408
#define BCN_ (B_*CN_)
#define BMN_ (B_*MN_)
#define NPG_ 392          // 128-px groups per image

typedef __attribute__((ext_vector_type(8))) short short8;       // 8 bf16
typedef __attribute__((ext_vector_type(4))) float f32x4;
typedef __attribute__((ext_vector_type(4))) unsigned int uint4v;

__device__ __forceinline__ float relu6f(float v){ return fminf(fmaxf(v,0.0f),6.0f); }
__device__ __forceinline__ float softplusf(float v){
  return v > 0.0f ? v + log1pf(expf(-v)) : log1pf(expf(v));
}
// RNE-pack two f32 -> one u32 of 2 bf16 (lo in low half)
__device__ __forceinline__ unsigned int rne2(float lo, float hi){
  unsigned int ul = __float_as_uint(lo); ul += 0x7FFFu + ((ul>>16)&1u);
  unsigned int uh = __float_as_uint(hi); uh += 0x7FFFu + ((uh>>16)&1u);
  return (ul>>16) | (uh & 0xFFFF0000u);
}

// ---------------------------------------------------------------------------
// MFMA helpers (round-8 verified)
// ---------------------------------------------------------------------------
__device__ __forceinline__ short8 bfrag(const unsigned short* __restrict__ L,
                                        int px, int c0){
  // B-frag: 8 consecutive c at one px, from bf16 LDS [c][128]
  const unsigned short* p = L + c0*128 + px;
  unsigned int w0 = (unsigned int)p[0]   | ((unsigned int)p[128]<<16);
  unsigned int w1 = (unsigned int)p[256] | ((unsigned int)p[384]<<16);
  unsigned int w2 = (unsigned int)p[512] | ((unsigned int)p[640]<<16);
  unsigned int w3 = (unsigned int)p[768] | ((unsigned int)p[896]<<16);
  uint4v q = {w0,w1,w2,w3};
  return __builtin_bit_cast(short8, q);
}
__device__ __forceinline__ short8 afrag(const float* __restrict__ W, int idx){
  // A-frag: 8 consecutive c of one oc-row, packed from fp32 global
  const float4 f0 = *(const float4*)(W + idx);
  const float4 f1 = *(const float4*)(W + idx + 4);
  uint4v q = {rne2(f0.x,f0.y), rne2(f0.z,f0.w), rne2(f1.x,f1.y), rne2(f1.z,f1.w)};
  return __builtin_bit_cast(short8, q);
}
__device__ __forceinline__ short8 zfrag(){
  uint4v q = {0u,0u,0u,0u};
  return __builtin_bit_cast(short8, q);
}

// ---------------------------------------------------------------------------
// K1 (MFMA, round-10 verified): h = relu6(bn(conv1x1(x))), K = softplus(conv1x1+kb)
// ---------------------------------------------------------------------------
__global__ __launch_bounds__(256) void k_fc1k(const float* __restrict__ x,
                                              const float* __restrict__ w,
                                              const float* __restrict__ bn,
                                              const float* __restrict__ kw,
                                              const float* __restrict__ kb,
                                              float* __restrict__ h,
                                              float* __restrict__ Kq)
{
  __shared__ unsigned short xls[64*128];   // bf16 [c][px]  16KB
  __shared__ float invb[2][64];
  const int tid  = threadIdx.x;
  const int b    = blockIdx.x / NPG_;
  const int pg   = blockIdx.x % NPG_;
  const int pix0 = pg*128;
  const float* xb = x + (size_t)b*CN_ + pix0;

  // stage x: thread = (c-within-slab, 4-px group), 8 slabs
  const int scp = tid >> 5;
  const int spx = (tid & 31) << 2;
  #pragma unroll
  for (int i = 0; i < 8; ++i) {
    const int c = i*8 + scp;
    const float4 xr = *(const float4*)(xb + (size_t)c*N_ + spx);
    *(uint2*)&xls[c*128 + spx] = make_uint2(rne2(xr.x,xr.y), rne2(xr.z,xr.w));
  }
  if (tid < 64) {
    const float inv = bn[tid] / sqrtf(bn[192+tid] + 1e-5f);
    invb[0][tid] = inv;
    invb[1][tid] = bn[64+tid] - bn[128+tid]*inv;
  }
  __syncthreads();

  const int lane = tid & 63, wv = tid >> 6;
  const int l15 = lane & 15, u = lane >> 4;
  const int pxw = wv*32;                       // wave's 32-px slice

  f32x4 acc[5][2];
  #pragma unroll
  for (int t = 0; t < 5; ++t)
    #pragma unroll
    for (int s2 = 0; s2 < 2; ++s2) acc[t][s2] = (f32x4){0.f,0.f,0.f,0.f};

  #pragma unroll
  for (int kk = 0; kk < 2; ++kk) {
    const int c0 = kk*32 + u*8;
    const short8 a0 = afrag(w, (0*16+l15)*64 + c0);
    const short8 a1 = afrag(w, (1*16+l15)*64 + c0);
    const short8 a2 = afrag(w, (2*16+l15)*64 + c0);
    const short8 a3 = afrag(w, (3*16+l15)*64 + c0);
    const short8 a4 = (l15 < 8) ? afrag(kw, l15*64 + c0) : zfrag();
    #pragma unroll
    for (int s2 = 0; s2 < 2; ++s2) {
      const short8 bx = bfrag(xls, pxw + s2*16 + l15, c0);
      acc[0][s2] = __builtin_amdgcn_mfma_f32_16x16x32_bf16(a0, bx, acc[0][s2], 0,0,0);
      acc[1][s2] = __builtin_amdgcn_mfma_f32_16x16x32_bf16(a1, bx, acc[1][s2], 0,0,0);
      acc[2][s2] = __builtin_amdgcn_mfma_f32_16x16x32_bf16(a2, bx, acc[2][s2], 0,0,0);
      acc[3][s2] = __builtin_amdgcn_mfma_f32_16x16x32_bf16(a3, bx, acc[3][s2], 0,0,0);
      acc[4][s2] = __builtin_amdgcn_mfma_f32_16x16x32_bf16(a4, bx, acc[4][s2], 0,0,0);
    }
  }

  // h epilogue (tiles 0..3): D col=l15(px), row=u*4+r(oc within tile)
  float* hb = h + (size_t)b*CN_ + pix0;
  #pragma unroll
  for (int t = 0; t < 4; ++t) {
    #pragma unroll
    for (int s2 = 0; s2 < 2; ++s2) {
      const int px = pxw + s2*16 + l15;
      #pragma unroll
      for (int r = 0; r < 4; ++r) {
        const int oc = t*16 + u*4 + r;
        hb[(size_t)oc*N_ + px] = relu6f(fmaf(acc[t][s2][r], invb[0][oc], invb[1][oc]));
      }
    }
  }
  // K epilogue (tile 4, valid rows 0..7 -> u<2): m = u*4+r
  if (u < 2) {
    float* Kb = Kq + (size_t)b*MN_ + pix0;
    #pragma unroll
    for (int s2 = 0; s2 < 2; ++s2) {
      const int px = pxw + s2*16 + l15;
      #pragma unroll
      for (int r = 0; r < 4; ++r) {
        const int m = u*4 + r;
        Kb[(size_t)m*N_ + px] = softplusf(acc[4][s2][r] + kb[m]);
      }
    }
  }
}

// ---------------------------------------------------------------------------
// K2: s = relu6(bn1(dw5x5(h))) + relu6(bn2(dw3x3(h)))   32x32 tile per (b,c)
// (round-0 verified version, byte-identical)
// ---------------------------------------------------------------------------
__global__ __launch_bounds__(256) void k_dw(const float* __restrict__ h,
                                            const float* __restrict__ w5,
                                            const float* __restrict__ w3,
                                            const float* __restrict__ bn1,
                                            const float* __restrict__ bn2,
                                            float* __restrict__ s)
{
  __shared__ float tile[36*37];
  const int tid = threadIdx.x;
  const int blk = blockIdx.x;              // B*C*49
  const int t   = blk % 49;
  const int bc  = blk / 49;
  const int c   = bc & 63;
  const int tx0 = (t % 7) * 32;
  const int ty0 = (t / 7) * 32;
  const float* hb = h + (size_t)bc * N_;

  for (int idx = tid; idx < 1296; idx += 256) {
    const int ly = idx / 36, lx = idx - ly*36;
    const int gy = ty0 + ly - 2, gx = tx0 + lx - 2;
    float v = 0.0f;
    if (gy >= 0 && gy < H_ && gx >= 0 && gx < W_) v = hb[gy*W_ + gx];
    tile[ly*37 + lx] = v;
  }
  __syncthreads();

  float w5r[25], w3r[9];
  #pragma unroll
  for (int i = 0; i < 25; ++i) w5r[i] = w5[c*25 + i];
  #pragma unroll
  for (int i = 0; i < 9; ++i)  w3r[i] = w3[c*9 + i];
  const float inv1 = bn1[c] / sqrtf(bn1[192+c] + 1e-5f);
  const float bet1 = bn1[64+c] - bn1[128+c]*inv1;
  const float inv2 = bn2[c] / sqrtf(bn2[192+c] + 1e-5f);
  const float bet2 = bn2[64+c] - bn2[128+c]*inv2;

  const int ty  = tid >> 3;
  const int tx4 = (tid & 7) << 2;
  float a5[4] = {0,0,0,0}, a3[4] = {0,0,0,0};
  #pragma unroll
  for (int dy = 0; dy < 5; ++dy) {
    float r[8];
    #pragma unroll
    for (int i = 0; i < 8; ++i) r[i] = tile[(ty+dy)*37 + tx4 + i];
    #pragma unroll
    for (int dx = 0; dx < 5; ++dx) {
      const float wv = w5r[dy*5+dx];
      #pragma unroll
      for (int p = 0; p < 4; ++p) a5[p] = fmaf(wv, r[p+dx], a5[p]);
    }
    if (dy >= 1 && dy <= 3) {
      #pragma unroll
      for (int dx = 1; dx <= 3; ++dx) {
        const float wv = w3r[(dy-1)*3+(dx-1)];
        #pragma unroll
        for (int p = 0; p < 4; ++p) a3[p] = fmaf(wv, r[p+dx], a3[p]);
      }
    }
  }
  float* sb = s + (size_t)bc * N_ + (ty0+ty)*W_ + tx0 + tx4;
  float4 o4;
  o4.x = relu6f(fmaf(a5[0],inv1,bet1)) + relu6f(fmaf(a3[0],inv2,bet2));
  o4.y = relu6f(fmaf(a5[1],inv1,bet1)) + relu6f(fmaf(a3[1],inv2,bet2));
  o4.z = relu6f(fmaf(a5[2],inv1,bet1)) + relu6f(fmaf(a3[2],inv2,bet2));
  o4.w = relu6f(fmaf(a5[3],inv1,bet1)) + relu6f(fmaf(a3[3],inv2,bet2));
  *(float4*)sb = o4;
}

// ---------------------------------------------------------------------------
// K3 (fused MFMA k_v + KV reduction): V = conv1x1(x,v_w)+v_b +
// relu6(bn(conv1x1(s,fc2_w))) held in D-frags (never written to global);
// then per-block KV partial via the round-3-verified 16-value halving
// butterfly over l15, per-block STORE (round-2 scheme, no atomics), plus
// Ksum partial from the staged K tile. Saves V's 102 MB round trip.
// LDS: xls/sls (32KB) reused after the MFMA loop as kvw (8KB) / kl (4KB).
// ---------------------------------------------------------------------------
__global__ __launch_bounds__(256) void k_vkv(const float* __restrict__ x,
                                             const float* __restrict__ s,
                                             const float* __restrict__ vw,
                                             const float* __restrict__ vb,
                                             const float* __restrict__ fw,
                                             const float* __restrict__ fbn,
                                             const float* __restrict__ Kq,
                                             float* __restrict__ kv_part,
                                             float* __restrict__ ks_part)
{
  __shared__ __align__(16) unsigned char smem[32768];
  unsigned short* xls = (unsigned short*)smem;            // 16KB  bf16 [c][px]
  unsigned short* sls = (unsigned short*)(smem + 16384);  // 16KB
  float* kvw = (float*)smem;                              // alias: [4][512] 8KB
  float* kl  = (float*)(smem + 16384);                    // alias: [8][128] 4KB
  __shared__ float invb[3][64];
  const int tid  = threadIdx.x;
  const int b    = blockIdx.x / NPG_;
  const int pg   = blockIdx.x % NPG_;
  const int pix0 = pg*128;
  const float* xb = x + (size_t)b*CN_ + pix0;
  const float* sb = s + (size_t)b*CN_ + pix0;

  // stage all 64 channels: thread = (c-within-slab, 4-px group), 8 slabs
  const int scp = tid >> 5;
  const int spx = (tid & 31) << 2;
  #pragma unroll
  for (int i = 0; i < 8; ++i) {
    const int c = i*8 + scp;
    const float4 xr = *(const float4*)(xb + (size_t)c*N_ + spx);
    const float4 sr = *(const float4*)(sb + (size_t)c*N_ + spx);
    *(uint2*)&xls[c*128 + spx] = make_uint2(rne2(xr.x,xr.y), rne2(xr.z,xr.w));
    *(uint2*)&sls[c*128 + spx] = make_uint2(rne2(sr.x,sr.y), rne2(sr.z,sr.w));
  }
  if (tid < 64) {
    const float inv = fbn[tid] / sqrtf(fbn[192+tid] + 1e-5f);
    invb[0][tid] = inv;
    invb[1][tid] = fbn[64+tid] - fbn[128+tid]*inv;
    invb[2][tid] = vb[tid];
  }
  __syncthreads();

  const int lane = tid & 63, wv = tid >> 6;
  const int l15 = lane & 15, u = lane >> 4;
  const int pxw = wv*32;                       // wave's 32-px slice

  f32x4 av[4][2], af[4][2];
  #pragma unroll
  for (int t = 0; t < 4; ++t)
    #pragma unroll
    for (int s2 = 0; s2 < 2; ++s2) { av[t][s2] = (f32x4){0.f,0.f,0.f,0.f};
                                     af[t][s2] = (f32x4){0.f,0.f,0.f,0.f}; }

  #pragma unroll
  for (int kk = 0; kk < 2; ++kk) {
    const int c0 = kk*32 + u*8;
    // x · vw
    {
      const short8 a0 = afrag(vw, (0*16+l15)*64 + c0);
      const short8 a1 = afrag(vw, (1*16+l15)*64 + c0);
      const short8 a2 = afrag(vw, (2*16+l15)*64 + c0);
      const short8 a3 = afrag(vw, (3*16+l15)*64 + c0);
      #pragma unroll
      for (int s2 = 0; s2 < 2; ++s2) {
        const short8 bx = bfrag(xls, pxw + s2*16 + l15, c0);
        av[0][s2] = __builtin_amdgcn_mfma_f32_16x16x32_bf16(a0, bx, av[0][s2], 0,0,0);
        av[1][s2] = __builtin_amdgcn_mfma_f32_16x16x32_bf16(a1, bx, av[1][s2], 0,0,0);
        av[2][s2] = __builtin_amdgcn_mfma_f32_16x16x32_bf16(a2, bx, av[2][s2], 0,0,0);
        av[3][s2] = __builtin_amdgcn_mfma_f32_16x16x32_bf16(a3, bx, av[3][s2], 0,0,0);
      }
    }
    // s · fc2
    {
      const short8 a0 = afrag(fw, (0*16+l15)*64 + c0);
      const short8 a1 = afrag(fw, (1*16+l15)*64 + c0);
      const short8 a2 = afrag(fw, (2*16+l15)*64 + c0);
      const short8 a3 = afrag(fw, (3*16+l15)*64 + c0);
      #pragma unroll
      for (int s2 = 0; s2 < 2; ++s2) {
        const short8 bs = bfrag(sls, pxw + s2*16 + l15, c0);
        af[0][s2] = __builtin_amdgcn_mfma_f32_16x16x32_bf16(a0, bs, af[0][s2], 0,0,0);
        af[1][s2] = __builtin_amdgcn_mfma_f32_16x16x32_bf16(a1, bs, af[1][s2], 0,0,0);
        af[2][s2] = __builtin_amdgcn_mfma_f32_16x16x32_bf16(a2, bs, af[2][s2], 0,0,0);
        af[3][s2] = __builtin_amdgcn_mfma_f32_16x16x32_bf16(a3, bs, af[3][s2], 0,0,0);
      }
    }
  }

  // V = av + vb + relu6(bn(af)) in place (registers only — no global write)
  #pragma unroll
  for (int t = 0; t < 4; ++t) {
    #pragma unroll
    for (int s2 = 0; s2 < 2; ++s2) {
      #pragma unroll
      for (int r = 0; r < 4; ++r) {
        const int oc = t*16 + u*4 + r;
        av[t][s2][r] = av[t][s2][r] + invb[2][oc]
            + relu6f(fmaf(af[t][s2][r], invb[0][oc], invb[1][oc]));
      }
    }
  }
  __syncthreads();                       // all waves done reading xls/sls

  // stage K tile [m=8][px=128] into kl (aliases sls)
  {
    const float* Kb = Kq + (size_t)b*MN_ + pix0;
    for (int idx = tid; idx < 1024; idx += 256)
      kl[idx] = Kb[(size_t)(idx >> 7)*N_ + (idx & 127)];
  }
  __syncthreads();                       // kl visible

  // Ksum partial: thread group of 32 per m (m = tid>>5), 4 px each
  {
    const int m = tid >> 5, p0 = tid & 31;
    float ss = kl[m*128 + p0] + kl[m*128 + p0 + 32]
             + kl[m*128 + p0 + 64] + kl[m*128 + p0 + 96];
    ss += __shfl_xor(ss, 1);  ss += __shfl_xor(ss, 2);
    ss += __shfl_xor(ss, 4);  ss += __shfl_xor(ss, 8);
    ss += __shfl_xor(ss, 16);
    if ((tid & 31) == 0)
      ks_part[(size_t)(b*NPG_ + pg)*8 + m] = ss;
  }

  // KV partial: per m, dots over lane's 2 px, then round-3-verified
  // 16-value halving butterfly over l15; writes kvw[wv] (aliases xls)
  const int jrev = 8*(l15&1) + 4*((l15>>1)&1) + 2*((l15>>2)&1) + ((l15>>3)&1);
  const int cdst = (jrev>>2)*16 + u*4 + (jrev&3);
  #pragma unroll
  for (int m = 0; m < 8; ++m) {
    const float k0 = kl[m*128 + pxw + l15];
    const float k1 = kl[m*128 + pxw + 16 + l15];
    float p[16];
    #pragma unroll
    for (int t = 0; t < 4; ++t)
      #pragma unroll
      for (int r = 0; r < 4; ++r)
        p[t*4+r] = fmaf(k0, av[t][0][r], k1 * av[t][1][r]);
    int nv = 16;
    #pragma unroll
    for (int mask = 1; mask <= 8; mask <<= 1) {
      nv >>= 1;
      const bool hi = (l15 & mask) != 0;
      #pragma unroll
      for (int i = 0; i < 8; ++i) {
        if (i < nv) {
          const float mine = hi ? p[i] : p[i+nv];
          const float th = __shfl_xor(mine, mask);
          p[i] = (hi ? p[i+nv] : p[i]) + th;
        }
      }
    }
    kvw[wv*512 + m*64 + cdst] = p[0];
  }
  __syncthreads();                       // kvw visible

  // coalesced 2KB dump of the block's KV partial (sum over 4 waves)
  float* kp = kv_part + (size_t)(b*NPG_ + pg)*512;
  kp[tid]       = (kvw[0*512 + tid]     + kvw[1*512 + tid])
                + (kvw[2*512 + tid]     + kvw[3*512 + tid]);
  kp[tid + 256] = (kvw[0*512 + tid+256] + kvw[1*512 + tid+256])
                + (kvw[2*512 + tid+256] + kvw[3*512 + tid+256]);
}

// ---------------------------------------------------------------------------
// K4: reduce per-block partials -> KV[b,512], Ksum[b,8]. (round-2 verified)
// ---------------------------------------------------------------------------
__global__ __launch_bounds__(256) void k_red(const float* __restrict__ kv_part,
                                             const float* __restrict__ ks_part,
                                             float* __restrict__ KV,
                                             float* __restrict__ Ksum)
{
  __shared__ float red[4][64];
  __shared__ float rks[256];
  const int blk = blockIdx.x;          // 32 blocks: b = blk>>3, seg = blk&7
  const int b = blk >> 3, seg = blk & 7;
  const int t = threadIdx.x;
  const int i = seg*64 + (t & 63);
  const int sl = t >> 6;               // 0..3
  const float* base = kv_part + (size_t)b*NPG_*512 + i;
  float a = 0.0f;
  for (int g = sl; g < NPG_; g += 4) a += base[(size_t)g*512];
  red[sl][t & 63] = a;
  __syncthreads();
  if (t < 64)
    KV[b*512 + seg*64 + t] = (red[0][t] + red[1][t]) + (red[2][t] + red[3][t]);

  if (seg == 0) {
    const int m = t & 7, g0 = t >> 3;  // 32 slices per m
    float s2 = 0.0f;
    for (int g = g0; g < NPG_; g += 32)
      s2 += ks_part[(size_t)b*NPG_*8 + g*8 + m];
    rks[t] = s2;
    __syncthreads();
    if (t < 8) {
      float s3 = 0.0f;
      #pragma unroll
      for (int j2 = 0; j2 < 32; ++j2) s3 += rks[j2*8 + t];
      Ksum[b*8 + t] = s3;
    }
  }
}

// ---------------------------------------------------------------------------
// K5: out = x + gamma * (Q^T KV) / (Q^T (Ksum+eps)), Q computed in-kernel
// from 32KB LDS x-stage. (round-7 verified version, byte-identical)
// ---------------------------------------------------------------------------
__global__ __launch_bounds__(256) void k_out(const float* __restrict__ x,
                                             const float* __restrict__ qw,
                                             const float* __restrict__ qb,
                                             const float* __restrict__ gamma,
                                             const float* __restrict__ KV,
                                             const float* __restrict__ Ksum,
                                             float* __restrict__ out)
{
  __shared__ float xs[64*128];                 // 32KB  xs[c][px]
  __shared__ __align__(16) float kvt[64*8];    // kvt[c][m]
  __shared__ __align__(16) float qwt[64*8];    // qwt[c][m]
  __shared__ float qs[8][128];
  __shared__ float scl[128];
  __shared__ float ksl[8];
  const int tid = threadIdx.x;
  const int b  = blockIdx.x / NPG_;
  const int pg = blockIdx.x % NPG_;
  const int pix0 = pg*128;
  const float* xb = x + (size_t)b*CN_ + pix0;

  for (int idx = tid; idx < 512; idx += 256) {
    const int m = idx >> 6, c = idx & 63;
    kvt[c*8 + m] = KV[b*512 + idx];
    qwt[c*8 + m] = qw[idx];
  }
  if (tid < 8) ksl[tid] = Ksum[b*8 + tid] + 1e-6f;
  #pragma unroll
  for (int i = 0; i < 8; ++i) {                // stage x: 2048 float4, coalesced
    const int idx = i*256 + tid;
    const int c = idx >> 5, p4 = (idx & 31) << 2;
    const float4 v = *(const float4*)(xb + (size_t)c*N_ + p4);
    *(float4*)&xs[c*128 + p4] = v;
  }
  __syncthreads();

  if (tid < 128) {                             // Q phase: 1 px per thread
    const int px = tid;
    float q[8] = {0,0,0,0,0,0,0,0};
    #pragma unroll 8
    for (int c = 0; c < 64; ++c) {
      const float xv = xs[c*128 + px];
      const float4 w0 = *(const float4*)&qwt[c*8];
      const float4 w1 = *(const float4*)&qwt[c*8+4];
      q[0] = fmaf(w0.x, xv, q[0]);
      q[1] = fmaf(w0.y, xv, q[1]);
      q[2] = fmaf(w0.z, xv, q[2]);
      q[3] = fmaf(w0.w, xv, q[3]);
      q[4] = fmaf(w1.x, xv, q[4]);
      q[5] = fmaf(w1.y, xv, q[5]);
      q[6] = fmaf(w1.z, xv, q[6]);
      q[7] = fmaf(w1.w, xv, q[7]);
    }
    float den = 0.0f;
    #pragma unroll
    for (int m = 0; m < 8; ++m) {
      q[m] = softplusf(q[m] + qb[m]);
      den  = fmaf(q[m], ksl[m], den);
      qs[m][px] = q[m];
    }
    scl[px] = gamma[0] / den;
  }
  __syncthreads();

  float* ob = out + (size_t)b*CN_ + pix0;
  #pragma unroll
  for (int i = 0; i < 32; ++i) {               // 8192 outputs / 256 threads
    const int idx = i*256 + tid;
    const int c = idx >> 7, px = idx & 127;
    const float4 k0 = *(const float4*)&kvt[c*8];
    const float4 k1 = *(const float4*)&kvt[c*8+4];
    float wv;
    wv = qs[0][px]*k0.x;
    wv = fmaf(qs[1][px], k0.y, wv);
    wv = fmaf(qs[2][px], k0.z, wv);
    wv = fmaf(qs[3][px], k0.w, wv);
    wv = fmaf(qs[4][px], k1.x, wv);
    wv = fmaf(qs[5][px], k1.y, wv);
    wv = fmaf(qs[6][px], k1.z, wv);
    wv = fmaf(qs[7][px], k1.w, wv);
    ob[(size_t)c*N_ + px] = fmaf(scl[px], wv, xs[c*128 + px]);
  }
}

// ---------------------------------------------------------------------------
extern "C" void kernel_launch(void* const* d_in, const int* in_sizes, int n_in,
                              void* d_out, int out_size, void* d_ws, size_t ws_size,
                              hipStream_t stream) {
  const float* x      = (const float*)d_in[0];
  const float* gamma  = (const float*)d_in[1];
  const float* q_w    = (const float*)d_in[2];
  const float* q_b    = (const float*)d_in[3];
  const float* k_w    = (const float*)d_in[4];
  const float* k_b    = (const float*)d_in[5];
  const float* v_w    = (const float*)d_in[6];
  const float* v_b    = (const float*)d_in[7];
  const float* fc1_w  = (const float*)d_in[8];
  const float* fc1_bn = (const float*)d_in[9];
  const float* c1_w   = (const float*)d_in[10];
  const float* c1_bn  = (const float*)d_in[11];
  const float* c2_w   = (const float*)d_in[12];
  const float* c2_bn  = (const float*)d_in[13];
  const float* fc2_w  = (const float*)d_in[14];
  const float* fc2_bn = (const float*)d_in[15];
  float* outp = (float*)d_out;

  float* ws      = (float*)d_ws;
  float* bufA    = ws;                         // h; dead after k_dw -> kv_part
  float* bufS    = ws + (size_t)BCN_;          // s
  float* bufK    = ws + (size_t)2*BCN_;        // K (B*M*N)
  float* ks_part = ws + (size_t)2*BCN_ + BMN_;             // 4*392*8
  float* kv      = ks_part + (size_t)B_*NPG_*8;            // 2048
  float* ksum    = kv + 2048;                              // 32
  float* kv_part = bufA;                       // alias h (4*392*512 floats)

  k_fc1k<<<dim3(B_*NPG_), dim3(256), 0, stream>>>(x, fc1_w, fc1_bn, k_w, k_b, bufA, bufK);
  k_dw  <<<dim3(B_*C_*49), dim3(256), 0, stream>>>(bufA, c1_w, c2_w, c1_bn, c2_bn, bufS);
  k_vkv <<<dim3(B_*NPG_), dim3(256), 0, stream>>>(x, bufS, v_w, v_b, fc2_w, fc2_bn, bufK, kv_part, ks_part);
  k_red <<<dim3(32), dim3(256), 0, stream>>>(kv_part, ks_part, kv, ksum);
  k_out <<<dim3(B_*NPG_), dim3(256), 0, stream>>>(x, q_w, q_b, gamma, kv, ksum, outp);
}

// Round 12
// 306.054 us; speedup vs baseline: 1.4572x; 1.4572x over previous
//
#include <hip/hip_runtime.h>
#include <math.h>

#define B_ 4
#define C_ 64
#define M_ 8
#define H_ 224
#define W_ 224
#define N_ (H_*W_)        // 50176
#define CN_ (C_*N_)       // 3211264
#define MN_ (M_*N_)       // 401408
#define BCN_ (B_*CN_)
#define BMN_ (B_*MN_)
#define NPG_ 392          // 128-px groups per image

typedef __attribute__((ext_vector_type(8))) short short8;       // 8 bf16
typedef __attribute__((ext_vector_type(4))) float f32x4;
typedef __attribute__((ext_vector_type(4))) unsigned int uint4v;

__device__ __forceinline__ float relu6f(float v){ return fminf(fmaxf(v,0.0f),6.0f); }
__device__ __forceinline__ float softplusf(float v){
  return v > 0.0f ? v + log1pf(expf(-v)) : log1pf(expf(v));
}
// RNE-pack two f32 -> one u32 of 2 bf16 (lo in low half)
__device__ __forceinline__ unsigned int rne2(float lo, float hi){
  unsigned int ul = __float_as_uint(lo); ul += 0x7FFFu + ((ul>>16)&1u);
  unsigned int uh = __float_as_uint(hi); uh += 0x7FFFu + ((uh>>16)&1u);
  return (ul>>16) | (uh & 0xFFFF0000u);
}
__device__ __forceinline__ unsigned short rne1(float f){
  unsigned int u = __float_as_uint(f); u += 0x7FFFu + ((u>>16)&1u);
  return (unsigned short)(u>>16);
}
__device__ __forceinline__ float bf2f(unsigned short v){
  return __uint_as_float(((unsigned int)v) << 16);
}

// ---------------------------------------------------------------------------
// MFMA helpers (round-8 verified)
// ---------------------------------------------------------------------------
__device__ __forceinline__ short8 bfrag(const unsigned short* __restrict__ L,
                                        int px, int c0){
  // B-frag: 8 consecutive c at one px, from bf16 LDS [c][128]
  const unsigned short* p = L + c0*128 + px;
  unsigned int w0 = (unsigned int)p[0]   | ((unsigned int)p[128]<<16);
  unsigned int w1 = (unsigned int)p[256] | ((unsigned int)p[384]<<16);
  unsigned int w2 = (unsigned int)p[512] | ((unsigned int)p[640]<<16);
  unsigned int w3 = (unsigned int)p[768] | ((unsigned int)p[896]<<16);
  uint4v q = {w0,w1,w2,w3};
  return __builtin_bit_cast(short8, q);
}
__device__ __forceinline__ short8 afrag(const float* __restrict__ W, int idx){
  // A-frag: 8 consecutive c of one oc-row, packed from fp32 global
  const float4 f0 = *(const float4*)(W + idx);
  const float4 f1 = *(const float4*)(W + idx + 4);
  uint4v q = {rne2(f0.x,f0.y), rne2(f0.z,f0.w), rne2(f1.x,f1.y), rne2(f1.z,f1.w)};
  return __builtin_bit_cast(short8, q);
}
__device__ __forceinline__ short8 zfrag(){
  uint4v q = {0u,0u,0u,0u};
  return __builtin_bit_cast(short8, q);
}

// ---------------------------------------------------------------------------
// K1 (MFMA, round-10 verified): h = relu6(bn(conv1x1(x))), K = softplus(conv1x1+kb)
// ---------------------------------------------------------------------------
__global__ __launch_bounds__(256) void k_fc1k(const float* __restrict__ x,
                                              const float* __restrict__ w,
                                              const float* __restrict__ bn,
                                              const float* __restrict__ kw,
                                              const float* __restrict__ kb,
                                              float* __restrict__ h,
                                              float* __restrict__ Kq)
{
  __shared__ unsigned short xls[64*128];   // bf16 [c][px]  16KB
  __shared__ float invb[2][64];
  const int tid  = threadIdx.x;
  const int b    = blockIdx.x / NPG_;
  const int pg   = blockIdx.x % NPG_;
  const int pix0 = pg*128;
  const float* xb = x + (size_t)b*CN_ + pix0;

  // stage x: thread = (c-within-slab, 4-px group), 8 slabs
  const int scp = tid >> 5;
  const int spx = (tid & 31) << 2;
  #pragma unroll
  for (int i = 0; i < 8; ++i) {
    const int c = i*8 + scp;
    const float4 xr = *(const float4*)(xb + (size_t)c*N_ + spx);
    *(uint2*)&xls[c*128 + spx] = make_uint2(rne2(xr.x,xr.y), rne2(xr.z,xr.w));
  }
  if (tid < 64) {
    const float inv = bn[tid] / sqrtf(bn[192+tid] + 1e-5f);
    invb[0][tid] = inv;
    invb[1][tid] = bn[64+tid] - bn[128+tid]*inv;
  }
  __syncthreads();

  const int lane = tid & 63, wv = tid >> 6;
  const int l15 = lane & 15, u = lane >> 4;
  const int pxw = wv*32;                       // wave's 32-px slice

  f32x4 acc[5][2];
  #pragma unroll
  for (int t = 0; t < 5; ++t)
    #pragma unroll
    for (int s2 = 0; s2 < 2; ++s2) acc[t][s2] = (f32x4){0.f,0.f,0.f,0.f};

  #pragma unroll
  for (int kk = 0; kk < 2; ++kk) {
    const int c0 = kk*32 + u*8;
    const short8 a0 = afrag(w, (0*16+l15)*64 + c0);
    const short8 a1 = afrag(w, (1*16+l15)*64 + c0);
    const short8 a2 = afrag(w, (2*16+l15)*64 + c0);
    const short8 a3 = afrag(w, (3*16+l15)*64 + c0);
    const short8 a4 = (l15 < 8) ? afrag(kw, l15*64 + c0) : zfrag();
    #pragma unroll
    for (int s2 = 0; s2 < 2; ++s2) {
      const short8 bx = bfrag(xls, pxw + s2*16 + l15, c0);
      acc[0][s2] = __builtin_amdgcn_mfma_f32_16x16x32_bf16(a0, bx, acc[0][s2], 0,0,0);
      acc[1][s2] = __builtin_amdgcn_mfma_f32_16x16x32_bf16(a1, bx, acc[1][s2], 0,0,0);
      acc[2][s2] = __builtin_amdgcn_mfma_f32_16x16x32_bf16(a2, bx, acc[2][s2], 0,0,0);
      acc[3][s2] = __builtin_amdgcn_mfma_f32_16x16x32_bf16(a3, bx, acc[3][s2], 0,0,0);
      acc[4][s2] = __builtin_amdgcn_mfma_f32_16x16x32_bf16(a4, bx, acc[4][s2], 0,0,0);
    }
  }

  // h epilogue (tiles 0..3): D col=l15(px), row=u*4+r(oc within tile)
  float* hb = h + (size_t)b*CN_ + pix0;
  #pragma unroll
  for (int t = 0; t < 4; ++t) {
    #pragma unroll
    for (int s2 = 0; s2 < 2; ++s2) {
      const int px = pxw + s2*16 + l15;
      #pragma unroll
      for (int r = 0; r < 4; ++r) {
        const int oc = t*16 + u*4 + r;
        hb[(size_t)oc*N_ + px] = relu6f(fmaf(acc[t][s2][r], invb[0][oc], invb[1][oc]));
      }
    }
  }
  // K epilogue (tile 4, valid rows 0..7 -> u<2): m = u*4+r
  if (u < 2) {
    float* Kb = Kq + (size_t)b*MN_ + pix0;
    #pragma unroll
    for (int s2 = 0; s2 < 2; ++s2) {
      const int px = pxw + s2*16 + l15;
      #pragma unroll
      for (int r = 0; r < 4; ++r) {
        const int m = u*4 + r;
        Kb[(size_t)m*N_ + px] = softplusf(acc[4][s2][r] + kb[m]);
      }
    }
  }
}

// ---------------------------------------------------------------------------
// K2: s = relu6(bn1(dw5x5(h))) + relu6(bn2(dw3x3(h)))   32x32 tile per (b,c)
// (round-0 verified version, byte-identical)
// ---------------------------------------------------------------------------
__global__ __launch_bounds__(256) void k_dw(const float* __restrict__ h,
                                            const float* __restrict__ w5,
                                            const float* __restrict__ w3,
                                            const float* __restrict__ bn1,
                                            const float* __restrict__ bn2,
                                            float* __restrict__ s)
{
  __shared__ float tile[36*37];
  const int tid = threadIdx.x;
  const int blk = blockIdx.x;              // B*C*49
  const int t   = blk % 49;
  const int bc  = blk / 49;
  const int c   = bc & 63;
  const int tx0 = (t % 7) * 32;
  const int ty0 = (t / 7) * 32;
  const float* hb = h + (size_t)bc * N_;

  for (int idx = tid; idx < 1296; idx += 256) {
    const int ly = idx / 36, lx = idx - ly*36;
    const int gy = ty0 + ly - 2, gx = tx0 + lx - 2;
    float v = 0.0f;
    if (gy >= 0 && gy < H_ && gx >= 0 && gx < W_) v = hb[gy*W_ + gx];
    tile[ly*37 + lx] = v;
  }
  __syncthreads();

  float w5r[25], w3r[9];
  #pragma unroll
  for (int i = 0; i < 25; ++i) w5r[i] = w5[c*25 + i];
  #pragma unroll
  for (int i = 0; i < 9; ++i)  w3r[i] = w3[c*9 + i];
  const float inv1 = bn1[c] / sqrtf(bn1[192+c] + 1e-5f);
  const float bet1 = bn1[64+c] - bn1[128+c]*inv1;
  const float inv2 = bn2[c] / sqrtf(bn2[192+c] + 1e-5f);
  const float bet2 = bn2[64+c] - bn2[128+c]*inv2;

  const int ty  = tid >> 3;
  const int tx4 = (tid & 7) << 2;
  float a5[4] = {0,0,0,0}, a3[4] = {0,0,0,0};
  #pragma unroll
  for (int dy = 0; dy < 5; ++dy) {
    float r[8];
    #pragma unroll
    for (int i = 0; i < 8; ++i) r[i] = tile[(ty+dy)*37 + tx4 + i];
    #pragma unroll
    for (int dx = 0; dx < 5; ++dx) {
      const float wv = w5r[dy*5+dx];
      #pragma unroll
      for (int p = 0; p < 4; ++p) a5[p] = fmaf(wv, r[p+dx], a5[p]);
    }
    if (dy >= 1 && dy <= 3) {
      #pragma unroll
      for (int dx = 1; dx <= 3; ++dx) {
        const float wv = w3r[(dy-1)*3+(dx-1)];
        #pragma unroll
        for (int p = 0; p < 4; ++p) a3[p] = fmaf(wv, r[p+dx], a3[p]);
      }
    }
  }
  float* sb = s + (size_t)bc * N_ + (ty0+ty)*W_ + tx0 + tx4;
  float4 o4;
  o4.x = relu6f(fmaf(a5[0],inv1,bet1)) + relu6f(fmaf(a3[0],inv2,bet2));
  o4.y = relu6f(fmaf(a5[1],inv1,bet1)) + relu6f(fmaf(a3[1],inv2,bet2));
  o4.z = relu6f(fmaf(a5[2],inv1,bet1)) + relu6f(fmaf(a3[2],inv2,bet2));
  o4.w = relu6f(fmaf(a5[3],inv1,bet1)) + relu6f(fmaf(a3[3],inv2,bet2));
  *(float4*)sb = o4;
}

// ---------------------------------------------------------------------------
// K3 (fused, v2): V in D-frags (no global write), then KV partial computed
// with a SECOND MFMA instead of the shuffle butterfly (rounds 3/11 showed
// 120-deep shfl chains at ~20% occupancy cost ~130us):
//   KV[m,c] = sum_px K[m,px]*V[c,px]  ->  mfma(A=K[m][px], B=V[px][c])
// V written back to LDS as bf16 [c][136-padded], K staged bf16 [8][136].
// A/B frags are contiguous b128 reads; pad 136 breaks stride-256B conflicts.
// Garbage A rows m>=8 only pollute D rows we never store. No atomics.
// ---------------------------------------------------------------------------
__global__ __launch_bounds__(256) void k_vkv(const float* __restrict__ x,
                                             const float* __restrict__ s,
                                             const float* __restrict__ vw,
                                             const float* __restrict__ vb,
                                             const float* __restrict__ fw,
                                             const float* __restrict__ fbn,
                                             const float* __restrict__ Kq,
                                             float* __restrict__ kv_part,
                                             float* __restrict__ ks_part)
{
  __shared__ __align__(16) unsigned char smem[32768];
  unsigned short* xls = (unsigned short*)smem;            // 16KB  bf16 [c][128]
  unsigned short* sls = (unsigned short*)(smem + 16384);  // 16KB
  // post-loop aliases:
  unsigned short* vls = (unsigned short*)smem;            // [64][136] 17408B
  unsigned short* klb = (unsigned short*)(smem + 17408);  // [8][136]  2176B
  __shared__ float kvw[4*512];                            // 8KB (separate)
  __shared__ float invb[3][64];
  const int tid  = threadIdx.x;
  const int b    = blockIdx.x / NPG_;
  const int pg   = blockIdx.x % NPG_;
  const int pix0 = pg*128;
  const float* xb = x + (size_t)b*CN_ + pix0;
  const float* sb = s + (size_t)b*CN_ + pix0;

  // stage all 64 channels: thread = (c-within-slab, 4-px group), 8 slabs
  const int scp = tid >> 5;
  const int spx = (tid & 31) << 2;
  #pragma unroll
  for (int i = 0; i < 8; ++i) {
    const int c = i*8 + scp;
    const float4 xr = *(const float4*)(xb + (size_t)c*N_ + spx);
    const float4 sr = *(const float4*)(sb + (size_t)c*N_ + spx);
    *(uint2*)&xls[c*128 + spx] = make_uint2(rne2(xr.x,xr.y), rne2(xr.z,xr.w));
    *(uint2*)&sls[c*128 + spx] = make_uint2(rne2(sr.x,sr.y), rne2(sr.z,sr.w));
  }
  if (tid < 64) {
    const float inv = fbn[tid] / sqrtf(fbn[192+tid] + 1e-5f);
    invb[0][tid] = inv;
    invb[1][tid] = fbn[64+tid] - fbn[128+tid]*inv;
    invb[2][tid] = vb[tid];
  }
  __syncthreads();

  const int lane = tid & 63, wv = tid >> 6;
  const int l15 = lane & 15, u = lane >> 4;
  const int pxw = wv*32;                       // wave's 32-px slice

  f32x4 av[4][2], af[4][2];
  #pragma unroll
  for (int t = 0; t < 4; ++t)
    #pragma unroll
    for (int s2 = 0; s2 < 2; ++s2) { av[t][s2] = (f32x4){0.f,0.f,0.f,0.f};
                                     af[t][s2] = (f32x4){0.f,0.f,0.f,0.f}; }

  #pragma unroll
  for (int kk = 0; kk < 2; ++kk) {
    const int c0 = kk*32 + u*8;
    // x · vw
    {
      const short8 a0 = afrag(vw, (0*16+l15)*64 + c0);
      const short8 a1 = afrag(vw, (1*16+l15)*64 + c0);
      const short8 a2 = afrag(vw, (2*16+l15)*64 + c0);
      const short8 a3 = afrag(vw, (3*16+l15)*64 + c0);
      #pragma unroll
      for (int s2 = 0; s2 < 2; ++s2) {
        const short8 bx = bfrag(xls, pxw + s2*16 + l15, c0);
        av[0][s2] = __builtin_amdgcn_mfma_f32_16x16x32_bf16(a0, bx, av[0][s2], 0,0,0);
        av[1][s2] = __builtin_amdgcn_mfma_f32_16x16x32_bf16(a1, bx, av[1][s2], 0,0,0);
        av[2][s2] = __builtin_amdgcn_mfma_f32_16x16x32_bf16(a2, bx, av[2][s2], 0,0,0);
        av[3][s2] = __builtin_amdgcn_mfma_f32_16x16x32_bf16(a3, bx, av[3][s2], 0,0,0);
      }
    }
    // s · fc2
    {
      const short8 a0 = afrag(fw, (0*16+l15)*64 + c0);
      const short8 a1 = afrag(fw, (1*16+l15)*64 + c0);
      const short8 a2 = afrag(fw, (2*16+l15)*64 + c0);
      const short8 a3 = afrag(fw, (3*16+l15)*64 + c0);
      #pragma unroll
      for (int s2 = 0; s2 < 2; ++s2) {
        const short8 bs = bfrag(sls, pxw + s2*16 + l15, c0);
        af[0][s2] = __builtin_amdgcn_mfma_f32_16x16x32_bf16(a0, bs, af[0][s2], 0,0,0);
        af[1][s2] = __builtin_amdgcn_mfma_f32_16x16x32_bf16(a1, bs, af[1][s2], 0,0,0);
        af[2][s2] = __builtin_amdgcn_mfma_f32_16x16x32_bf16(a2, bs, af[2][s2], 0,0,0);
        af[3][s2] = __builtin_amdgcn_mfma_f32_16x16x32_bf16(a3, bs, af[3][s2], 0,0,0);
      }
    }
  }
  __syncthreads();                       // all waves done reading xls/sls

  // V = av + vb + relu6(bn(af)) -> straight into vls (bf16, padded rows)
  #pragma unroll
  for (int t = 0; t < 4; ++t) {
    #pragma unroll
    for (int s2 = 0; s2 < 2; ++s2) {
      const int px = pxw + s2*16 + l15;
      #pragma unroll
      for (int r = 0; r < 4; ++r) {
        const int oc = t*16 + u*4 + r;
        const float vv = av[t][s2][r] + invb[2][oc]
            + relu6f(fmaf(af[t][s2][r], invb[0][oc], invb[1][oc]));
        vls[oc*136 + px] = rne1(vv);
      }
    }
  }
  // stage K as bf16 into klb[m][136]
  {
    const float* Kb = Kq + (size_t)b*MN_ + pix0;
    for (int idx = tid; idx < 512; idx += 256) {
      const int m = idx >> 6, p2 = (idx & 63) << 1;
      ((unsigned int*)(klb + m*136))[p2 >> 1] =
          rne2(Kb[(size_t)m*N_ + p2], Kb[(size_t)m*N_ + p2 + 1]);
    }
  }
  __syncthreads();                       // vls/klb visible

  // Ksum partial: 32 lanes per m (short shuffle chain — the fast pattern)
  {
    const int m = tid >> 5, p0 = tid & 31;
    float ss = bf2f(klb[m*136 + p0])      + bf2f(klb[m*136 + p0 + 32])
             + bf2f(klb[m*136 + p0 + 64]) + bf2f(klb[m*136 + p0 + 96]);
    ss += __shfl_xor(ss, 1);  ss += __shfl_xor(ss, 2);
    ss += __shfl_xor(ss, 4);  ss += __shfl_xor(ss, 8);
    ss += __shfl_xor(ss, 16);
    if ((tid & 31) == 0)
      ks_part[(size_t)(b*NPG_ + pg)*8 + m] = ss;
  }

  // KV partial via MFMA: A = K (row m=l15, k=px), B = V (col c, k=px).
  // Frags are contiguous b128 reads. Wave wv covers px window [pxw, pxw+32).
  f32x4 kvd[4];
  {
    const short8 ka = *(const short8*)(klb + l15*136 + pxw + u*8);
    #pragma unroll
    for (int tc = 0; tc < 4; ++tc) {
      const short8 vbf = *(const short8*)(vls + (tc*16 + l15)*136 + pxw + u*8);
      kvd[tc] = __builtin_amdgcn_mfma_f32_16x16x32_bf16(ka, vbf, (f32x4){0.f,0.f,0.f,0.f}, 0,0,0);
    }
  }
  // D layout: col=l15 (c within tile), row=u*4+rr (m); valid m<8 -> u<2
  if (u < 2) {
    #pragma unroll
    for (int tc = 0; tc < 4; ++tc)
      #pragma unroll
      for (int rr = 0; rr < 4; ++rr)
        kvw[wv*512 + (u*4+rr)*64 + tc*16 + l15] = kvd[tc][rr];
  }
  __syncthreads();                       // kvw visible

  // coalesced 2KB dump of the block's KV partial (sum over 4 waves)
  float* kp = kv_part + (size_t)(b*NPG_ + pg)*512;
  kp[tid]       = (kvw[0*512 + tid]     + kvw[1*512 + tid])
                + (kvw[2*512 + tid]     + kvw[3*512 + tid]);
  kp[tid + 256] = (kvw[0*512 + tid+256] + kvw[1*512 + tid+256])
                + (kvw[2*512 + tid+256] + kvw[3*512 + tid+256]);
}

// ---------------------------------------------------------------------------
// K4: reduce per-block partials -> KV[b,512], Ksum[b,8]. (round-2 verified)
// ---------------------------------------------------------------------------
__global__ __launch_bounds__(256) void k_red(const float* __restrict__ kv_part,
                                             const float* __restrict__ ks_part,
                                             float* __restrict__ KV,
                                             float* __restrict__ Ksum)
{
  __shared__ float red[4][64];
  __shared__ float rks[256];
  const int blk = blockIdx.x;          // 32 blocks: b = blk>>3, seg = blk&7
  const int b = blk >> 3, seg = blk & 7;
  const int t = threadIdx.x;
  const int i = seg*64 + (t & 63);
  const int sl = t >> 6;               // 0..3
  const float* base = kv_part + (size_t)b*NPG_*512 + i;
  float a = 0.0f;
  for (int g = sl; g < NPG_; g += 4) a += base[(size_t)g*512];
  red[sl][t & 63] = a;
  __syncthreads();
  if (t < 64)
    KV[b*512 + seg*64 + t] = (red[0][t] + red[1][t]) + (red[2][t] + red[3][t]);

  if (seg == 0) {
    const int m = t & 7, g0 = t >> 3;  // 32 slices per m
    float s2 = 0.0f;
    for (int g = g0; g < NPG_; g += 32)
      s2 += ks_part[(size_t)b*NPG_*8 + g*8 + m];
    rks[t] = s2;
    __syncthreads();
    if (t < 8) {
      float s3 = 0.0f;
      #pragma unroll
      for (int j2 = 0; j2 < 32; ++j2) s3 += rks[j2*8 + t];
      Ksum[b*8 + t] = s3;
    }
  }
}

// ---------------------------------------------------------------------------
// K5: out = x + gamma * (Q^T KV) / (Q^T (Ksum+eps)), Q computed in-kernel
// from 32KB LDS x-stage. (round-7 verified version, byte-identical)
// ---------------------------------------------------------------------------
__global__ __launch_bounds__(256) void k_out(const float* __restrict__ x,
                                             const float* __restrict__ qw,
                                             const float* __restrict__ qb,
                                             const float* __restrict__ gamma,
                                             const float* __restrict__ KV,
                                             const float* __restrict__ Ksum,
                                             float* __restrict__ out)
{
  __shared__ float xs[64*128];                 // 32KB  xs[c][px]
  __shared__ __align__(16) float kvt[64*8];    // kvt[c][m]
  __shared__ __align__(16) float qwt[64*8];    // qwt[c][m]
  __shared__ float qs[8][128];
  __shared__ float scl[128];
  __shared__ float ksl[8];
  const int tid = threadIdx.x;
  const int b  = blockIdx.x / NPG_;
  const int pg = blockIdx.x % NPG_;
  const int pix0 = pg*128;
  const float* xb = x + (size_t)b*CN_ + pix0;

  for (int idx = tid; idx < 512; idx += 256) {
    const int m = idx >> 6, c = idx & 63;
    kvt[c*8 + m] = KV[b*512 + idx];
    qwt[c*8 + m] = qw[idx];
  }
  if (tid < 8) ksl[tid] = Ksum[b*8 + tid] + 1e-6f;
  #pragma unroll
  for (int i = 0; i < 8; ++i) {                // stage x: 2048 float4, coalesced
    const int idx = i*256 + tid;
    const int c = idx >> 5, p4 = (idx & 31) << 2;
    const float4 v = *(const float4*)(xb + (size_t)c*N_ + p4);
    *(float4*)&xs[c*128 + p4] = v;
  }
  __syncthreads();

  if (tid < 128) {                             // Q phase: 1 px per thread
    const int px = tid;
    float q[8] = {0,0,0,0,0,0,0,0};
    #pragma unroll 8
    for (int c = 0; c < 64; ++c) {
      const float xv = xs[c*128 + px];
      const float4 w0 = *(const float4*)&qwt[c*8];
      const float4 w1 = *(const float4*)&qwt[c*8+4];
      q[0] = fmaf(w0.x, xv, q[0]);
      q[1] = fmaf(w0.y, xv, q[1]);
      q[2] = fmaf(w0.z, xv, q[2]);
      q[3] = fmaf(w0.w, xv, q[3]);
      q[4] = fmaf(w1.x, xv, q[4]);
      q[5] = fmaf(w1.y, xv, q[5]);
      q[6] = fmaf(w1.z, xv, q[6]);
      q[7] = fmaf(w1.w, xv, q[7]);
    }
    float den = 0.0f;
    #pragma unroll
    for (int m = 0; m < 8; ++m) {
      q[m] = softplusf(q[m] + qb[m]);
      den  = fmaf(q[m], ksl[m], den);
      qs[m][px] = q[m];
    }
    scl[px] = gamma[0] / den;
  }
  __syncthreads();

  float* ob = out + (size_t)b*CN_ + pix0;
  #pragma unroll
  for (int i = 0; i < 32; ++i) {               // 8192 outputs / 256 threads
    const int idx = i*256 + tid;
    const int c = idx >> 7, px = idx & 127;
    const float4 k0 = *(const float4*)&kvt[c*8];
    const float4 k1 = *(const float4*)&kvt[c*8+4];
    float wv;
    wv = qs[0][px]*k0.x;
    wv = fmaf(qs[1][px], k0.y, wv);
    wv = fmaf(qs[2][px], k0.z, wv);
    wv = fmaf(qs[3][px], k0.w, wv);
    wv = fmaf(qs[4][px], k1.x, wv);
    wv = fmaf(qs[5][px], k1.y, wv);
    wv = fmaf(qs[6][px], k1.z, wv);
    wv = fmaf(qs[7][px], k1.w, wv);
    ob[(size_t)c*N_ + px] = fmaf(scl[px], wv, xs[c*128 + px]);
  }
}

// ---------------------------------------------------------------------------
extern "C" void kernel_launch(void* const* d_in, const int* in_sizes, int n_in,
                              void* d_out, int out_size, void* d_ws, size_t ws_size,
                              hipStream_t stream) {
  const float* x      = (const float*)d_in[0];
  const float* gamma  = (const float*)d_in[1];
  const float* q_w    = (const float*)d_in[2];
  const float* q_b    = (const float*)d_in[3];
  const float* k_w    = (const float*)d_in[4];
  const float* k_b    = (const float*)d_in[5];
  const float* v_w    = (const float*)d_in[6];
  const float* v_b    = (const float*)d_in[7];
  const float* fc1_w  = (const float*)d_in[8];
  const float* fc1_bn = (const float*)d_in[9];
  const float* c1_w   = (const float*)d_in[10];
  const float* c1_bn  = (const float*)d_in[11];
  const float* c2_w   = (const float*)d_in[12];
  const float* c2_bn  = (const float*)d_in[13];
  const float* fc2_w  = (const float*)d_in[14];
  const float* fc2_bn = (const float*)d_in[15];
  float* outp = (float*)d_out;

  float* ws      = (float*)d_ws;
  float* bufA    = ws;                         // h; dead after k_dw -> kv_part
  float* bufS    = ws + (size_t)BCN_;          // s
  float* bufK    = ws + (size_t)2*BCN_;        // K (B*M*N)
  float* ks_part = ws + (size_t)2*BCN_ + BMN_;             // 4*392*8
  float* kv      = ks_part + (size_t)B_*NPG_*8;            // 2048
  float* ksum    = kv + 2048;                              // 32
  float* kv_part = bufA;                       // alias h (4*392*512 floats)

  k_fc1k<<<dim3(B_*NPG_), dim3(256), 0, stream>>>(x, fc1_w, fc1_bn, k_w, k_b, bufA, bufK);
  k_dw  <<<dim3(B_*C_*49), dim3(256), 0, stream>>>(bufA, c1_w, c2_w, c1_bn, c2_bn, bufS);
  k_vkv <<<dim3(B_*NPG_), dim3(256), 0, stream>>>(x, bufS, v_w, v_b, fc2_w, fc2_bn, bufK, kv_part, ks_part);
  k_red <<<dim3(32), dim3(256), 0, stream>>>(kv_part, ks_part, kv, ksum);
  k_out <<<dim3(B_*NPG_), dim3(256), 0, stream>>>(x, q_w, q_b, gamma, kv, ksum, outp);
}